// Round 4
// baseline (419.087 us; speedup 1.0000x reference)
//
#include <hip/hip_runtime.h>
#include <hip/hip_bf16.h>
#include <cstdint>

// MHA: B=2, S=2048, H=16, Dk=64, D=1024.
// v2 (resubmit, infra outage): casts fused into GEMM staging (fp32 global ->
// bf16 LDS), workspace 32MB.
// Pipeline: 3x proj GEMM (head-split epilogue), flash attention, out-proj GEMM.
// All MFMA = v_mfma_f32_16x16x32_bf16, verified layouts:
// A lane: row=l&15, k=8*(l>>4)+r ; B lane: col=l&15, k=8*(l>>4)+r ;
// C/D: col=l&15, row=(l>>4)*4+reg.

typedef __attribute__((ext_vector_type(8))) short bf16x8;
typedef __attribute__((ext_vector_type(4))) float f32x4;

#define MFMA16(a, b, c) __builtin_amdgcn_mfma_f32_16x16x32_bf16((a), (b), (c), 0, 0, 0)

static __device__ __forceinline__ unsigned short f2bf(float f) {
  unsigned u = __float_as_uint(f);
  u += 0x7FFFu + ((u >> 16) & 1u);
  return (unsigned short)(u >> 16);
}

static __device__ __forceinline__ bf16x8 cvt8(const float* p) {
  bf16x8 r;
#pragma unroll
  for (int i = 0; i < 8; ++i) r[i] = (short)f2bf(p[i]);
  return r;
}

// C = A[M,K] * W[N,K]^T + bias.  A is fp32 (aBf16=0) or bf16 (aBf16=1); W fp32.
// mode 0: out bf16 head-split [BH][S][64]
// mode 1: out bf16 transposed-per-head [BH][64][S]
// mode 2: out fp32 [M][N]
__global__ __launch_bounds__(256) void gemm_bt(const void* __restrict__ Ap,
                                               const float* __restrict__ W,
                                               const float* __restrict__ bias,
                                               unsigned short* __restrict__ outBf,
                                               float* __restrict__ outF,
                                               int K, int N, int mode, int aBf16) {
  __shared__ __align__(16) unsigned short As[128][72];  // +8 pad: 2-way conflicts only
  __shared__ __align__(16) unsigned short Bs[128][72];
  const int tid = threadIdx.x;
  const int lane = tid & 63, wid = tid >> 6;
  const int m0 = blockIdx.x * 128, n0 = blockIdx.y * 128;
  const int wm = (wid >> 1) * 64, wn = (wid & 1) * 64;
  const int lr = lane & 15, lg = lane >> 4;

  f32x4 acc[4][4];
  for (int i = 0; i < 4; ++i)
    for (int j = 0; j < 4; ++j) acc[i][j] = (f32x4){0.f, 0.f, 0.f, 0.f};

  const int srow = tid >> 1;         // 0..127
  const int scol = (tid & 1) * 32;   // 0 / 32

  for (int k0 = 0; k0 < K; k0 += 64) {
    bf16x8 av[4], bv[4];
    if (aBf16) {
      const unsigned short* ga = (const unsigned short*)Ap + (size_t)(m0 + srow) * K + k0 + scol;
#pragma unroll
      for (int i = 0; i < 4; ++i) av[i] = *(const bf16x8*)(ga + i * 8);
    } else {
      const float* ga = (const float*)Ap + (size_t)(m0 + srow) * K + k0 + scol;
      float ta[32];
#pragma unroll
      for (int i = 0; i < 8; ++i) *(float4*)&ta[i * 4] = *(const float4*)(ga + i * 4);
#pragma unroll
      for (int i = 0; i < 4; ++i) av[i] = cvt8(&ta[i * 8]);
    }
    {
      const float* gb = W + (size_t)(n0 + srow) * K + k0 + scol;
      float tb[32];
#pragma unroll
      for (int i = 0; i < 8; ++i) *(float4*)&tb[i * 4] = *(const float4*)(gb + i * 4);
#pragma unroll
      for (int i = 0; i < 4; ++i) bv[i] = cvt8(&tb[i * 8]);
    }
    __syncthreads();  // previous tile fully consumed
#pragma unroll
    for (int i = 0; i < 4; ++i) {
      *(bf16x8*)&As[srow][scol + i * 8] = av[i];
      *(bf16x8*)&Bs[srow][scol + i * 8] = bv[i];
    }
    __syncthreads();
#pragma unroll
    for (int kc = 0; kc < 64; kc += 32) {
      bf16x8 af[4], bfr[4];
#pragma unroll
      for (int mt = 0; mt < 4; ++mt) af[mt] = *(const bf16x8*)&As[wm + mt * 16 + lr][kc + lg * 8];
#pragma unroll
      for (int nt = 0; nt < 4; ++nt) bfr[nt] = *(const bf16x8*)&Bs[wn + nt * 16 + lr][kc + lg * 8];
#pragma unroll
      for (int mt = 0; mt < 4; ++mt)
#pragma unroll
        for (int nt = 0; nt < 4; ++nt) acc[mt][nt] = MFMA16(af[mt], bfr[nt], acc[mt][nt]);
    }
  }

#pragma unroll
  for (int mt = 0; mt < 4; ++mt)
#pragma unroll
    for (int nt = 0; nt < 4; ++nt) {
      const int gn = n0 + wn + nt * 16 + lr;
      const float bv2 = bias[gn];
#pragma unroll
      for (int j = 0; j < 4; ++j) {
        const int gm = m0 + wm + mt * 16 + lg * 4 + j;
        const float v = acc[mt][nt][j] + bv2;
        if (mode == 2) {
          outF[(size_t)gm * N + gn] = v;
        } else {
          const int b = gm >> 11, s = gm & 2047;
          const int h = gn >> 6, d = gn & 63;
          const size_t off = (mode == 0)
                                 ? (((size_t)(b * 16 + h) * 2048 + s) * 64 + d)
                                 : (((size_t)(b * 16 + h) * 64 + d) * 2048 + s);
          outBf[off] = f2bf(v);
        }
      }
    }
}

// Flash attention. grid (32 qtiles, 32 bh). 4 waves/block, 16 q-rows/wave.
__global__ __launch_bounds__(256) void attn_kernel(const unsigned short* __restrict__ Qh,
                                                   const unsigned short* __restrict__ Kh,
                                                   const unsigned short* __restrict__ Vt,
                                                   unsigned short* __restrict__ AO) {
  __shared__ __align__(16) unsigned short P[4][16][40];  // per-wave P tile, padded
  const int lane = threadIdx.x & 63, wid = threadIdx.x >> 6;
  const int lr = lane & 15, lg = lane >> 4;
  const int bh = blockIdx.y;
  const int q0 = blockIdx.x * 64 + wid * 16;
  const unsigned short* Qp = Qh + (size_t)bh * 2048 * 64;
  const unsigned short* Kp = Kh + (size_t)bh * 2048 * 64;
  const unsigned short* Vp = Vt + (size_t)bh * 64 * 2048;

  bf16x8 qf0 = *(const bf16x8*)(Qp + (size_t)(q0 + lr) * 64 + lg * 8);
  bf16x8 qf1 = *(const bf16x8*)(Qp + (size_t)(q0 + lr) * 64 + 32 + lg * 8);

  f32x4 o[4];
  for (int dc = 0; dc < 4; ++dc) o[dc] = (f32x4){0.f, 0.f, 0.f, 0.f};
  float mrun[4], lrun[4];
  for (int j = 0; j < 4; ++j) { mrun[j] = -INFINITY; lrun[j] = 0.f; }

  for (int kv0 = 0; kv0 < 2048; kv0 += 32) {
    f32x4 s0 = (f32x4){0.f, 0.f, 0.f, 0.f};
    f32x4 s1 = (f32x4){0.f, 0.f, 0.f, 0.f};
    bf16x8 k00 = *(const bf16x8*)(Kp + (size_t)(kv0 + lr) * 64 + lg * 8);
    bf16x8 k01 = *(const bf16x8*)(Kp + (size_t)(kv0 + lr) * 64 + 32 + lg * 8);
    bf16x8 k10 = *(const bf16x8*)(Kp + (size_t)(kv0 + 16 + lr) * 64 + lg * 8);
    bf16x8 k11 = *(const bf16x8*)(Kp + (size_t)(kv0 + 16 + lr) * 64 + 32 + lg * 8);
    s0 = MFMA16(qf0, k00, s0);
    s0 = MFMA16(qf1, k01, s0);
    s1 = MFMA16(qf0, k10, s1);
    s1 = MFMA16(qf1, k11, s1);

    float al[4];
#pragma unroll
    for (int j = 0; j < 4; ++j) {
      const float sa = s0[j] * 0.125f;  // 1/sqrt(64)
      const float sb = s1[j] * 0.125f;
      float mx = fmaxf(sa, sb);
      for (int d = 1; d < 16; d <<= 1) mx = fmaxf(mx, __shfl_xor(mx, d, 64));
      const float mn = fmaxf(mrun[j], mx);
      const float a = __expf(mrun[j] - mn);
      const float p0 = __expf(sa - mn);
      const float p1 = __expf(sb - mn);
      float rs = p0 + p1;
      for (int d = 1; d < 16; d <<= 1) rs += __shfl_xor(rs, d, 64);
      lrun[j] = lrun[j] * a + rs;
      mrun[j] = mn;
      al[j] = a;
      P[wid][lg * 4 + j][lr] = f2bf(p0);
      P[wid][lg * 4 + j][16 + lr] = f2bf(p1);
    }
#pragma unroll
    for (int dc = 0; dc < 4; ++dc)
#pragma unroll
      for (int j = 0; j < 4; ++j) o[dc][j] *= al[j];

    __syncthreads();  // P writes visible (cross-lane within wave)
    bf16x8 pa = *(const bf16x8*)&P[wid][lr][lg * 8];
#pragma unroll
    for (int dc = 0; dc < 4; ++dc) {
      bf16x8 vf = *(const bf16x8*)(Vp + (size_t)(dc * 16 + lr) * 2048 + kv0 + lg * 8);
      o[dc] = MFMA16(pa, vf, o[dc]);
    }
    __syncthreads();  // pa consumed before next-iter P overwrite
  }

  const int b = bh >> 4, h = bh & 15;
#pragma unroll
  for (int j = 0; j < 4; ++j) {
    const float inv = 1.0f / lrun[j];
    const int s = q0 + lg * 4 + j;
    const size_t row = (size_t)(b * 2048 + s) * 1024 + h * 64;
#pragma unroll
    for (int dc = 0; dc < 4; ++dc) AO[row + dc * 16 + lr] = f2bf(o[dc][j] * inv);
  }
}

extern "C" void kernel_launch(void* const* d_in, const int* in_sizes, int n_in,
                              void* d_out, int out_size, void* d_ws, size_t ws_size,
                              hipStream_t stream) {
  const float* q  = (const float*)d_in[0];
  const float* k  = (const float*)d_in[1];
  const float* v  = (const float*)d_in[2];
  const float* Wq = (const float*)d_in[3];
  const float* bq = (const float*)d_in[4];
  const float* Wk = (const float*)d_in[5];
  const float* bk = (const float*)d_in[6];
  const float* Wv = (const float*)d_in[7];
  const float* bv = (const float*)d_in[8];
  const float* Wo = (const float*)d_in[9];
  const float* bo = (const float*)d_in[10];
  float* out = (float*)d_out;

  char* w = (char*)d_ws;
  const size_t MB = 1024ull * 1024ull;
  unsigned short* QH = (unsigned short*)(w + 0 * MB);   // [32][2048][64] bf16
  unsigned short* KH = (unsigned short*)(w + 8 * MB);   // [32][2048][64] bf16
  unsigned short* VT = (unsigned short*)(w + 16 * MB);  // [32][64][2048] bf16
  unsigned short* AO = (unsigned short*)(w + 24 * MB);  // [4096][1024]  bf16

  dim3 ggrid(32, 8);
  gemm_bt<<<ggrid, 256, 0, stream>>>(q, Wq, bq, QH, nullptr, 1024, 1024, 0, 0);
  gemm_bt<<<ggrid, 256, 0, stream>>>(k, Wk, bk, KH, nullptr, 1024, 1024, 0, 0);
  gemm_bt<<<ggrid, 256, 0, stream>>>(v, Wv, bv, VT, nullptr, 1024, 1024, 1, 0);

  attn_kernel<<<dim3(32, 32), 256, 0, stream>>>(QH, KH, VT, AO);

  gemm_bt<<<ggrid, 256, 0, stream>>>(AO, Wo, bo, nullptr, out, 1024, 1024, 2, 1);
}